// Round 3
// baseline (973.006 us; speedup 1.0000x reference)
//
#include <hip/hip_runtime.h>
#include <stdint.h>

// Problem constants
#define B_   128
#define T_   32
#define V_   32000
#define E_   128
#define H_   256
#define F_   2048
#define G4   1024   // 4*H
#define EF   2176   // E+F

typedef __attribute__((ext_vector_type(8))) short bh8;    // 8 x bf16 (raw bits)
typedef __attribute__((ext_vector_type(4))) short bh4;
typedef __attribute__((ext_vector_type(4))) float floatx4;

typedef __attribute__((address_space(1))) const void gv_t; // global
typedef __attribute__((address_space(3))) void lv_t;       // LDS

__device__ __forceinline__ short f2bf(float f) {
    union { float f; uint32_t u; } v; v.f = f;
    uint32_t r = (v.u + 0x7fffu + ((v.u >> 16) & 1u)) >> 16;   // RNE
    return (short)(uint16_t)r;
}

__device__ __forceinline__ float fast_tanh(float x) {
    // tanh(x) = 1 - 2/(1+e^{2x}); saturates correctly for |x| large.
    return 1.f - 2.f / (1.f + __expf(2.f * x));
}

// ---------------------------------------------------------------------------
// Elementwise fp32 -> bf16 convert. grid*1024 elements exactly.
// ---------------------------------------------------------------------------
__global__ __launch_bounds__(256) void cvt_f2b(
    const float* __restrict__ in, short* __restrict__ out)
{
    const size_t i = (size_t)blockIdx.x * 256 + threadIdx.x;
    const floatx4 v = *(const floatx4*)&in[i * 4];
    bh4 o;
    o[0] = f2bf(v[0]); o[1] = f2bf(v[1]); o[2] = f2bf(v[2]); o[3] = f2bf(v[3]);
    *(bh4*)&out[i * 4] = o;
}

// ---------------------------------------------------------------------------
// Transpose + convert: in fp32 (R x C) row-major -> out bf16 (C x R).
// ---------------------------------------------------------------------------
__global__ __launch_bounds__(256) void transpose_f2b(
    const float* __restrict__ in, short* __restrict__ out, int R, int C)
{
    __shared__ float tile[64][68];
    const int c0 = blockIdx.x * 64, r0 = blockIdx.y * 64;
    const int x = threadIdx.x & 15, y = threadIdx.x >> 4;
#pragma unroll
    for (int i = 0; i < 4; i++) {
        const int r = y + i * 16;
        *(floatx4*)&tile[r][x * 4] = *(const floatx4*)&in[(size_t)(r0 + r) * C + c0 + x * 4];
    }
    __syncthreads();
#pragma unroll
    for (int i = 0; i < 4; i++) {
        const int cc = y + i * 16;
        bh4 v;
        v[0] = f2bf(tile[x * 4 + 0][cc]);
        v[1] = f2bf(tile[x * 4 + 1][cc]);
        v[2] = f2bf(tile[x * 4 + 2][cc]);
        v[3] = f2bf(tile[x * 4 + 3][cc]);
        *(bh4*)&out[(size_t)(c0 + cc) * R + r0 + x * 4] = v;
    }
}

// ---------------------------------------------------------------------------
// Gather embedding rows + convert: out[(t*B + b)][e] = bf16(emb[captions[b][t]][e])
// ---------------------------------------------------------------------------
__global__ __launch_bounds__(256) void gather_embed(
    const int* __restrict__ captions, const float* __restrict__ emb,
    short* __restrict__ out)
{
    const int r = blockIdx.x * 16 + (threadIdx.x >> 4);   // r = t*B + b
    const int chunk = threadIdx.x & 15;
    const int t = r >> 7, b = r & 127;
    const int cap = captions[b * T_ + t];
    const floatx4* src = (const floatx4*)&emb[(size_t)cap * E_];
    const floatx4 a = src[chunk * 2], c = src[chunk * 2 + 1];
    bh8 o;
    o[0] = f2bf(a[0]); o[1] = f2bf(a[1]); o[2] = f2bf(a[2]); o[3] = f2bf(a[3]);
    o[4] = f2bf(c[0]); o[5] = f2bf(c[1]); o[6] = f2bf(c[2]); o[7] = f2bf(c[3]);
    ((bh8*)out)[(size_t)r * 16 + chunk] = o;
}

// ---------------------------------------------------------------------------
// Shared NT GEMM tile body: C(128x128 tile) = A(MxK) @ B(NxK)^T.
// global_load_lds (16 B) staging, mfma_16x16x32_bf16, fp32 acc.
// ntc: nontemporal fp32 C stores (streaming output, keep B tiles in L2).
// rowbias: per-row additive term rowbias[(m&127)*G4 + n] (folds fg into eg).
// ---------------------------------------------------------------------------
#define TM 128
#define TN 128
#define BKG 64

__device__ __forceinline__ void gemm_body(
    const short* __restrict__ A, int lda,
    const short* __restrict__ B, int ldb,
    int K,
    float* __restrict__ Cf, short* __restrict__ Cb, int ldc,
    const float* __restrict__ bias1, const float* __restrict__ bias2,
    const float* __restrict__ rowbias,
    int bx, int by, short* As, short* Bs, int ntc)
{
    const int tid  = threadIdx.x;
    const int lane = tid & 63, quad = lane >> 4, l15 = lane & 15;
    const int wv   = tid >> 6;
    const int wr   = wv >> 1, wc = wv & 1;
    const short* Ab = A + (size_t)by * TM * lda;
    const short* Bb = B + (size_t)bx * TN * ldb;
    const int srow = tid >> 3;            // 32 rows per issue
    const int skof = (tid & 7) << 3;      // 8 shorts (16 B)

    floatx4 zero = {0.f, 0.f, 0.f, 0.f};
    floatx4 acc[4][4];
#pragma unroll
    for (int i = 0; i < 4; i++)
#pragma unroll
        for (int j = 0; j < 4; j++) acc[i][j] = zero;

    for (int k0 = 0; k0 < K; k0 += BKG) {
        __syncthreads();
#pragma unroll
        for (int j = 0; j < 4; j++) {
            const int r = j * 32 + srow;
            // LDS dest is wave-uniform base + lane*16 (matches [row][k] layout)
            __builtin_amdgcn_global_load_lds(
                (gv_t*)&Ab[(size_t)r * lda + k0 + skof],
                (lv_t*)&As[(j * 32 + wv * 8) * BKG], 16, 0, 0);
            __builtin_amdgcn_global_load_lds(
                (gv_t*)&Bb[(size_t)r * ldb + k0 + skof],
                (lv_t*)&Bs[(j * 32 + wv * 8) * BKG], 16, 0, 0);
        }
        __syncthreads();
#pragma unroll
        for (int ks = 0; ks < 2; ks++) {
            bh8 af[4], bfr[4];
#pragma unroll
            for (int i = 0; i < 4; i++)
                af[i] = *(const bh8*)&As[(wr * 64 + i * 16 + l15) * BKG + ks * 32 + quad * 8];
#pragma unroll
            for (int j = 0; j < 4; j++)
                bfr[j] = *(const bh8*)&Bs[(wc * 64 + j * 16 + l15) * BKG + ks * 32 + quad * 8];
#pragma unroll
            for (int i = 0; i < 4; i++)
#pragma unroll
                for (int j = 0; j < 4; j++)
                    acc[i][j] = __builtin_amdgcn_mfma_f32_16x16x32_bf16(af[i], bfr[j], acc[i][j], 0, 0, 0);
        }
    }

    // C/D layout: col = lane&15, row = quad*4 + reg  [m89-verified]
#pragma unroll
    for (int i = 0; i < 4; i++) {
        const int m = by * TM + wr * 64 + i * 16 + quad * 4;
#pragma unroll
        for (int j = 0; j < 4; j++) {
            const int n = bx * TN + wc * 64 + j * 16 + l15;
            float bias = 0.f;
            if (bias1) bias += bias1[n];
            if (bias2) bias += bias2[n];
#pragma unroll
            for (int r = 0; r < 4; r++) {
                float v = acc[i][j][r] + bias;
                if (rowbias) v += rowbias[(size_t)((m + r) & 127) * G4 + n];
                if (Cf) {
                    if (ntc) __builtin_nontemporal_store(v, &Cf[(size_t)(m + r) * ldc + n]);
                    else     Cf[(size_t)(m + r) * ldc + n] = v;
                } else {
                    Cb[(size_t)(m + r) * ldc + n] = f2bf(v);
                }
            }
        }
    }
}

__global__ __launch_bounds__(256) void gemm_nt(
    const short* __restrict__ A, int lda,
    const short* __restrict__ B, int ldb, int K,
    float* __restrict__ Cf, short* __restrict__ Cb, int ldc,
    const float* __restrict__ bias1, const float* __restrict__ bias2,
    const float* __restrict__ rowbias,
    int swz, int ntc)
{
    __shared__ short As[TM * BKG];
    __shared__ short Bs[TN * BKG];
    int bx = blockIdx.x, by = blockIdx.y;
    if (swz) {
        // XCD-chunked bijective remap (nwg % 8 == 0 for the swizzled call site).
        // Each XCD gets a contiguous bx-chunk, by-fastest, so its B panel
        // plus the whole A matrix (~2 MB) stay L2-resident per XCD.
        const int nx = gridDim.x, ny = gridDim.y;
        const int lin = by * nx + bx;
        const int q = (nx * ny) >> 3;
        const int n = (lin & 7) * q + (lin >> 3);
        bx = n / ny;
        by = n - bx * ny;
    }
    gemm_body(A, lda, B, ldb, K, Cf, Cb, ldc, bias1, bias2, rowbias, bx, by, As, Bs, ntc);
}

// One launch for the three K=2048 init GEMMs (h0, c0, feat-gates). 12 blocks.
__global__ __launch_bounds__(256) void init_gemms(
    const short* __restrict__ featB, const short* __restrict__ iHt,
    const short* __restrict__ iCt, const short* __restrict__ WihB,
    short* __restrict__ h0, float* __restrict__ c0, float* __restrict__ fg,
    const float* __restrict__ initH_b, const float* __restrict__ initC_b,
    const float* __restrict__ b_ih, const float* __restrict__ b_hh)
{
    __shared__ short As[TM * BKG];
    __shared__ short Bs[TN * BKG];
    const int bid = blockIdx.x;
    if (bid < 2)
        gemm_body(featB, F_, iHt, F_, F_, nullptr, h0, H_, initH_b, nullptr, nullptr, bid, 0, As, Bs, 0);
    else if (bid < 4)
        gemm_body(featB, F_, iCt, F_, F_, c0, nullptr, H_, initC_b, nullptr, nullptr, bid - 2, 0, As, Bs, 0);
    else
        gemm_body(featB, F_, WihB + E_, EF, F_, fg, nullptr, G4, b_ih, b_hh, nullptr, bid - 4, 0, As, Bs, 0);
}

// ---------------------------------------------------------------------------
// Batch-partitioned LSTM recurrence — ZERO inter-block communication.
// 32 blocks x 256 threads; block owns batches [4*bx, 4*bx+4).
// W_hh (512 KB bf16) partitioned three ways per step:
//   j =  0..7  : persistent register cache (256 VGPR/lane, 1 wave/SIMD,
//                total ~400 VGPR < 450 no-spill threshold [m08/m24])
//   j =  8..11 : persistent LDS cache (128 KB, XOR-swizzled vs bank conflicts)
//   j = 12..15 : streamed from global (L2-hot), 128 KB/block/step
// eg already contains fg + b_ih + b_hh (folded in the eg-GEMM epilogue).
// h lives in LDS (M=16 mfma rows, 4 real); c in registers.
// ---------------------------------------------------------------------------
#define HS 272       // padded h row stride in shorts
#define WG_REG 8     // j-groups cached in registers (j = 0..7)
#define WG_LDS 4     // j-groups cached in LDS (j = 8..11)

__global__ __launch_bounds__(256, 1) void recurrence3(
    const short* __restrict__ Whh,   // (1024 x 256) bf16
    const float* __restrict__ eg,    // (T*B x 1024) fp32: emb gates + fg + biases
    const short* __restrict__ h0,    // (128 x 256) bf16
    const float* __restrict__ c0,    // (128 x 256) fp32
    short* __restrict__ Hall)        // (B*T x 256) bf16, row b*T+t
{
    __shared__ short hs[16 * HS];                    // 8704 B
    __shared__ float Gs[4 * G4];                     // 16384 B
    __shared__ short wlds[WG_LDS * 4 * 16 * 256];    // 131072 B  (total 152.5 KB)
    const int tid  = threadIdx.x;
    const int lane = tid & 63, quad = lane >> 4, l15 = lane & 15, wv = tid >> 6;
    const int b0   = blockIdx.x * 4;
    const int u    = tid;            // pointwise: thread owns unit u, all 4 batches

    // ---- Prologue ----
    // h0 -> LDS (zero the pad rows), c0 -> regs
#pragma unroll
    for (int b = 0; b < 4; b++)
        hs[b * HS + tid] = h0[(size_t)(b0 + b) * H_ + tid];
#pragma unroll
    for (int rr = 4; rr < 16; rr++)
        hs[rr * HS + tid] = 0;
    float c[4];
#pragma unroll
    for (int b = 0; b < 4; b++) c[b] = c0[(size_t)(b0 + b) * H_ + u];

    // LDS W_hh cache fill: 256 rows (4 groups x 4 waves x 16), one row/thread.
    // XOR swizzle (row&7)<<3 shorts on the k-offset, same involution on read.
    {
        const int g = tid >> 6, wv_r = (tid >> 4) & 3, r15 = tid & 15;
        const int grow = wv_r * 256 + (WG_REG + g) * 16 + r15;
        const int swz = (r15 & 7) << 3;
#pragma unroll
        for (int kk = 0; kk < 32; kk++) {
            const bh8 w = *(const bh8*)&Whh[(size_t)grow * H_ + kk * 8];
            *(bh8*)&wlds[tid * 256 + ((kk * 8) ^ swz)] = w;
        }
    }

    // Register W_hh cache: j = 0..7 for this wave's gate cols
    bh8 wcache[WG_REG][8];
#pragma unroll
    for (int j = 0; j < WG_REG; j++) {
        const short* wrow = &Whh[(size_t)(wv * 256 + j * 16 + l15) * H_ + quad * 8];
#pragma unroll
        for (int s = 0; s < 8; s++)
            wcache[j][s] = *(const bh8*)&wrow[s * 32];
    }
    __syncthreads();

    const int swzr = (l15 & 7) << 3;
    const floatx4 zero = {0.f, 0.f, 0.f, 0.f};
    for (int t = 0; t < T_; t++) {
        // Prefetch emb-gate terms early (independent of this step's MFMA)
        float egv[4][4];
#pragma unroll
        for (int b = 0; b < 4; b++)
#pragma unroll
            for (int g = 0; g < 4; g++)
                egv[b][g] = eg[(size_t)(t * B_ + b0 + b) * G4 + g * H_ + u];

        // A-fragments from LDS h (A[m=l15][k=quad*8+j])
        bh8 af[8];
#pragma unroll
        for (int s = 0; s < 8; s++)
            af[s] = *(const bh8*)&hs[l15 * HS + s * 32 + quad * 8];

        // MFMA accumulate. Wave wv covers gate cols [wv*256, wv*256+256).
        floatx4 acc[16];
#pragma unroll
        for (int j = 0; j < 16; j++) acc[j] = zero;
        // j = 12..15 streamed from global first (loads issue early)
#pragma unroll
        for (int j = WG_REG + WG_LDS; j < 16; j++) {
            const short* wrow = &Whh[(size_t)(wv * 256 + j * 16 + l15) * H_ + quad * 8];
#pragma unroll
            for (int s = 0; s < 8; s++)
                acc[j] = __builtin_amdgcn_mfma_f32_16x16x32_bf16(
                    af[s], *(const bh8*)&wrow[s * 32], acc[j], 0, 0, 0);
        }
        // j = 8..11 from the LDS cache (swizzled)
#pragma unroll
        for (int g = 0; g < WG_LDS; g++) {
            const short* wp = &wlds[((g * 4 + wv) * 16 + l15) * 256];
#pragma unroll
            for (int s = 0; s < 8; s++)
                acc[WG_REG + g] = __builtin_amdgcn_mfma_f32_16x16x32_bf16(
                    af[s], *(const bh8*)&wp[(s * 32 + quad * 8) ^ swzr], acc[WG_REG + g], 0, 0, 0);
        }
        // j = 0..7 from the register cache (no memory traffic)
#pragma unroll
        for (int j = 0; j < WG_REG; j++)
#pragma unroll
            for (int s = 0; s < 8; s++)
                acc[j] = __builtin_amdgcn_mfma_f32_16x16x32_bf16(
                    af[s], wcache[j][s], acc[j], 0, 0, 0);

        // Batch rows 0-3 live in quad 0 (row = quad*4 + reg)
        if (quad == 0) {
#pragma unroll
            for (int j = 0; j < 16; j++) {
                const int col = wv * 256 + j * 16 + l15;
#pragma unroll
                for (int r = 0; r < 4; r++)
                    Gs[r * G4 + col] = acc[j][r];
            }
        }
        __syncthreads();

        // LSTM pointwise: unit u, batches 0-3, fp32 state
#pragma unroll
        for (int b = 0; b < 4; b++) {
            const float xi = Gs[b * G4 + u]          + egv[b][0];
            const float xf = Gs[b * G4 + H_ + u]     + egv[b][1];
            const float xg = Gs[b * G4 + 2 * H_ + u] + egv[b][2];
            const float xo = Gs[b * G4 + 3 * H_ + u] + egv[b][3];
            const float ig  = 1.f / (1.f + __expf(-xi));
            const float fgt = 1.f / (1.f + __expf(-xf));
            const float gg  = fast_tanh(xg);
            const float og  = 1.f / (1.f + __expf(-xo));
            c[b] = fgt * c[b] + ig * gg;
            const float h = og * fast_tanh(c[b]);
            const short hb = f2bf(h);
            hs[b * HS + u] = hb;
            Hall[(size_t)((b0 + b) * T_ + t) * H_ + u] = hb;
        }
        __syncthreads();
    }
}

// ---------------------------------------------------------------------------
// Host launcher
// ---------------------------------------------------------------------------
extern "C" void kernel_launch(void* const* d_in, const int* in_sizes, int n_in,
                              void* d_out, int out_size, void* d_ws, size_t ws_size,
                              hipStream_t stream)
{
    (void)in_sizes; (void)n_in; (void)out_size; (void)ws_size;
    const float* features   = (const float*)d_in[0];
    const int*   captions   = (const int*)  d_in[1];
    const float* embeddings = (const float*)d_in[2];
    const float* W_ih       = (const float*)d_in[3];
    const float* b_ih       = (const float*)d_in[4];
    const float* W_hh       = (const float*)d_in[5];
    const float* b_hh       = (const float*)d_in[6];
    const float* fc_W       = (const float*)d_in[7];
    const float* fc_b       = (const float*)d_in[8];
    // d_in[9..14] (Wa/Ua/va): softmax over singleton axis == 1 -> dead.
    const float* initH_W    = (const float*)d_in[15];
    const float* initH_b    = (const float*)d_in[16];
    const float* initC_W    = (const float*)d_in[17];
    const float* initC_b    = (const float*)d_in[18];
    float* out = (float*)d_out;

    char* ws = (char*)d_ws;
    size_t off = 0;
    auto alloc = [&](size_t bytes) -> void* {
        void* p = ws + off; off += (bytes + 255) & ~(size_t)255; return p;
    };
    // X region: eg (fp32, 16.78 MB) during recurrence, then fcWt (bf16, 16.38 MB)
    void*  X      = alloc((size_t)B_ * T_ * G4 * 4);
    float* eg     = (float*)X;
    short* fcWt   = (short*)X;
    short* featB  = (short*)alloc((size_t)B_ * F_ * 2);
    short* WihB   = (short*)alloc((size_t)G4 * EF * 2);
    short* WhhB   = (short*)alloc((size_t)G4 * H_ * 2);
    short* iHt    = (short*)alloc((size_t)H_ * F_ * 2);
    short* iCt    = (short*)alloc((size_t)H_ * F_ * 2);
    short* embB   = (short*)alloc((size_t)B_ * T_ * E_ * 2);
    float* fg     = (float*)alloc((size_t)B_ * G4 * 4);
    short* h0buf  = (short*)alloc((size_t)B_ * H_ * 2);
    float* c0f    = (float*)alloc((size_t)B_ * H_ * 4);
    short* Hall   = (short*)alloc((size_t)B_ * T_ * H_ * 2);
    // total ~28.2 MB

    cvt_f2b<<<dim3(B_ * F_ / 1024), 256, 0, stream>>>(features, featB);
    cvt_f2b<<<dim3(G4 * EF / 1024), 256, 0, stream>>>(W_ih, WihB);
    cvt_f2b<<<dim3(G4 * H_ / 1024), 256, 0, stream>>>(W_hh, WhhB);
    transpose_f2b<<<dim3(H_ / 64, F_ / 64), 256, 0, stream>>>(initH_W, iHt, F_, H_);
    transpose_f2b<<<dim3(H_ / 64, F_ / 64), 256, 0, stream>>>(initC_W, iCt, F_, H_);
    gather_embed<<<dim3(B_ * T_ / 16), 256, 0, stream>>>(captions, embeddings, embB);

    // h0 / c0 / feat-gates in one 12-block launch
    init_gemms<<<dim3(12), 256, 0, stream>>>(featB, iHt, iCt, WihB,
                                             h0buf, c0f, fg,
                                             initH_b, initC_b, b_ih, b_hh);
    // emb gates for all timesteps: (T*B x 128) @ W_ih[:,:E]^T -> (T*B x 1024),
    // with fg (feat-gates + both biases) folded in per row (rowbias keyed m&127)
    gemm_nt<<<dim3(G4 / TN, B_ * T_ / TM), 256, 0, stream>>>(embB, E_, WihB, EF, E_,
                                                             eg, nullptr, G4, nullptr, nullptr,
                                                             fg, 0, 0);
    // Zero-sync batch-partitioned recurrence (W_hh: 8 j-groups in regs,
    // 4 in LDS, 4 streamed from L2)
    recurrence3<<<dim3(32), 256, 0, stream>>>(WhhB, eg, h0buf, c0f, Hall);

    // eg is dead now; build fc_W^T in the same region, then the big projection
    transpose_f2b<<<dim3(V_ / 64, H_ / 64), 256, 0, stream>>>(fc_W, fcWt, H_, V_);
    // XCD-chunked swizzle (8000 blocks % 8 == 0) + nontemporal fp32 C stores
    gemm_nt<<<dim3(V_ / TN, B_ * T_ / TM), 256, 0, stream>>>(Hall, H_, fcWt, H_, H_,
                                                             out, nullptr, V_, fc_b, nullptr,
                                                             nullptr, 1, 1);
}

// Round 4
// 972.690 us; speedup vs baseline: 1.0003x; 1.0003x over previous
//
#include <hip/hip_runtime.h>
#include <stdint.h>

// Problem constants
#define B_   128
#define T_   32
#define V_   32000
#define E_   128
#define H_   256
#define F_   2048
#define G4   1024   // 4*H
#define EF   2176   // E+F

typedef __attribute__((ext_vector_type(8))) short bh8;    // 8 x bf16 (raw bits)
typedef __attribute__((ext_vector_type(4))) short bh4;
typedef __attribute__((ext_vector_type(4))) float floatx4;

typedef __attribute__((address_space(1))) const void gv_t; // global
typedef __attribute__((address_space(3))) void lv_t;       // LDS

__device__ __forceinline__ short f2bf(float f) {
    union { float f; uint32_t u; } v; v.f = f;
    uint32_t r = (v.u + 0x7fffu + ((v.u >> 16) & 1u)) >> 16;   // RNE
    return (short)(uint16_t)r;
}

__device__ __forceinline__ float fast_tanh(float x) {
    // tanh(x) = 1 - 2/(1+e^{2x}); saturates correctly for |x| large.
    return 1.f - 2.f / (1.f + __expf(2.f * x));
}

// ---------------------------------------------------------------------------
// Fused fp32 -> bf16 convert for the three weight/feature buffers.
// Block ranges: [0,256) features, [256,2432) W_ih, [2432,2688) W_hh.
// ---------------------------------------------------------------------------
__global__ __launch_bounds__(256) void cvt3(
    const float* __restrict__ f, const float* __restrict__ wih,
    const float* __restrict__ whh,
    short* __restrict__ fB, short* __restrict__ wihB, short* __restrict__ whhB)
{
    const int blk = blockIdx.x;
    const float* src; short* dst; size_t base;
    if (blk < 256)       { src = f;   dst = fB;   base = (size_t)blk * 1024; }
    else if (blk < 2432) { src = wih; dst = wihB; base = (size_t)(blk - 256) * 1024; }
    else                 { src = whh; dst = whhB; base = (size_t)(blk - 2432) * 1024; }
    const size_t i = base + (size_t)threadIdx.x * 4;
    const floatx4 v = *(const floatx4*)&src[i];
    bh4 o;
    o[0] = f2bf(v[0]); o[1] = f2bf(v[1]); o[2] = f2bf(v[2]); o[3] = f2bf(v[3]);
    *(bh4*)&dst[i] = o;
}

// ---------------------------------------------------------------------------
// Transpose + convert: in fp32 (R x C) row-major -> out bf16 (C x R).
// ---------------------------------------------------------------------------
__device__ __forceinline__ void transpose_body(
    const float* __restrict__ in, short* __restrict__ out, int R, int C,
    int bx, int by)
{
    __shared__ float tile[64][68];
    const int c0 = bx * 64, r0 = by * 64;
    const int x = threadIdx.x & 15, y = threadIdx.x >> 4;
#pragma unroll
    for (int i = 0; i < 4; i++) {
        const int r = y + i * 16;
        *(floatx4*)&tile[r][x * 4] = *(const floatx4*)&in[(size_t)(r0 + r) * C + c0 + x * 4];
    }
    __syncthreads();
#pragma unroll
    for (int i = 0; i < 4; i++) {
        const int cc = y + i * 16;
        bh4 v;
        v[0] = f2bf(tile[x * 4 + 0][cc]);
        v[1] = f2bf(tile[x * 4 + 1][cc]);
        v[2] = f2bf(tile[x * 4 + 2][cc]);
        v[3] = f2bf(tile[x * 4 + 3][cc]);
        *(bh4*)&out[(size_t)(c0 + cc) * R + r0 + x * 4] = v;
    }
}

__global__ __launch_bounds__(256) void transpose_f2b(
    const float* __restrict__ in, short* __restrict__ out, int R, int C)
{
    transpose_body(in, out, R, C, blockIdx.x, blockIdx.y);
}

// Both init-weight transposes (initH_W, initC_W) in one launch (z selects).
__global__ __launch_bounds__(256) void transpose2_f2b(
    const float* __restrict__ inA, short* __restrict__ outA,
    const float* __restrict__ inB, short* __restrict__ outB)
{
    const float* in = blockIdx.z ? inB : inA;
    short* out      = blockIdx.z ? outB : outA;
    transpose_body(in, out, F_, H_, blockIdx.x, blockIdx.y);
}

// ---------------------------------------------------------------------------
// Gather embedding rows + convert: out[(t*B + b)][e] = bf16(emb[captions[b][t]][e])
// ---------------------------------------------------------------------------
__global__ __launch_bounds__(256) void gather_embed(
    const int* __restrict__ captions, const float* __restrict__ emb,
    short* __restrict__ out)
{
    const int r = blockIdx.x * 16 + (threadIdx.x >> 4);   // r = t*B + b
    const int chunk = threadIdx.x & 15;
    const int t = r >> 7, b = r & 127;
    const int cap = captions[b * T_ + t];
    const floatx4* src = (const floatx4*)&emb[(size_t)cap * E_];
    const floatx4 a = src[chunk * 2], c = src[chunk * 2 + 1];
    bh8 o;
    o[0] = f2bf(a[0]); o[1] = f2bf(a[1]); o[2] = f2bf(a[2]); o[3] = f2bf(a[3]);
    o[4] = f2bf(c[0]); o[5] = f2bf(c[1]); o[6] = f2bf(c[2]); o[7] = f2bf(c[3]);
    ((bh8*)out)[(size_t)r * 16 + chunk] = o;
}

// ---------------------------------------------------------------------------
// Shared NT GEMM tile body: C(128x128 tile) = A(MxK) @ B(NxK)^T.
// global_load_lds (16 B) staging, mfma_16x16x32_bf16, fp32 acc.
// ntc: nontemporal fp32 C stores (streaming output, keep B tiles in L2).
// rowbias: per-row additive term rowbias[(m&127)*G4 + n] (folds fg into eg).
// ---------------------------------------------------------------------------
#define TM 128
#define TN 128
#define BKG 64

__device__ __forceinline__ void gemm_body(
    const short* __restrict__ A, int lda,
    const short* __restrict__ B, int ldb,
    int K,
    float* __restrict__ Cf, short* __restrict__ Cb, int ldc,
    const float* __restrict__ bias1, const float* __restrict__ bias2,
    const float* __restrict__ rowbias,
    int bx, int by, short* As, short* Bs, int ntc)
{
    const int tid  = threadIdx.x;
    const int lane = tid & 63, quad = lane >> 4, l15 = lane & 15;
    const int wv   = tid >> 6;
    const int wr   = wv >> 1, wc = wv & 1;
    const short* Ab = A + (size_t)by * TM * lda;
    const short* Bb = B + (size_t)bx * TN * ldb;
    const int srow = tid >> 3;            // 32 rows per issue
    const int skof = (tid & 7) << 3;      // 8 shorts (16 B)

    floatx4 zero = {0.f, 0.f, 0.f, 0.f};
    floatx4 acc[4][4];
#pragma unroll
    for (int i = 0; i < 4; i++)
#pragma unroll
        for (int j = 0; j < 4; j++) acc[i][j] = zero;

    for (int k0 = 0; k0 < K; k0 += BKG) {
        __syncthreads();
#pragma unroll
        for (int j = 0; j < 4; j++) {
            const int r = j * 32 + srow;
            // LDS dest is wave-uniform base + lane*16 (matches [row][k] layout)
            __builtin_amdgcn_global_load_lds(
                (gv_t*)&Ab[(size_t)r * lda + k0 + skof],
                (lv_t*)&As[(j * 32 + wv * 8) * BKG], 16, 0, 0);
            __builtin_amdgcn_global_load_lds(
                (gv_t*)&Bb[(size_t)r * ldb + k0 + skof],
                (lv_t*)&Bs[(j * 32 + wv * 8) * BKG], 16, 0, 0);
        }
        __syncthreads();
#pragma unroll
        for (int ks = 0; ks < 2; ks++) {
            bh8 af[4], bfr[4];
#pragma unroll
            for (int i = 0; i < 4; i++)
                af[i] = *(const bh8*)&As[(wr * 64 + i * 16 + l15) * BKG + ks * 32 + quad * 8];
#pragma unroll
            for (int j = 0; j < 4; j++)
                bfr[j] = *(const bh8*)&Bs[(wc * 64 + j * 16 + l15) * BKG + ks * 32 + quad * 8];
#pragma unroll
            for (int i = 0; i < 4; i++)
#pragma unroll
                for (int j = 0; j < 4; j++)
                    acc[i][j] = __builtin_amdgcn_mfma_f32_16x16x32_bf16(af[i], bfr[j], acc[i][j], 0, 0, 0);
        }
    }

    // C/D layout: col = lane&15, row = quad*4 + reg  [m89-verified]
#pragma unroll
    for (int i = 0; i < 4; i++) {
        const int m = by * TM + wr * 64 + i * 16 + quad * 4;
#pragma unroll
        for (int j = 0; j < 4; j++) {
            const int n = bx * TN + wc * 64 + j * 16 + l15;
            float bias = 0.f;
            if (bias1) bias += bias1[n];
            if (bias2) bias += bias2[n];
#pragma unroll
            for (int r = 0; r < 4; r++) {
                float v = acc[i][j][r] + bias;
                if (rowbias) v += rowbias[(size_t)((m + r) & 127) * G4 + n];
                if (Cf) {
                    if (ntc) __builtin_nontemporal_store(v, &Cf[(size_t)(m + r) * ldc + n]);
                    else     Cf[(size_t)(m + r) * ldc + n] = v;
                } else {
                    Cb[(size_t)(m + r) * ldc + n] = f2bf(v);
                }
            }
        }
    }
}

__global__ __launch_bounds__(256) void gemm_nt(
    const short* __restrict__ A, int lda,
    const short* __restrict__ B, int ldb, int K,
    float* __restrict__ Cf, short* __restrict__ Cb, int ldc,
    const float* __restrict__ bias1, const float* __restrict__ bias2,
    const float* __restrict__ rowbias,
    int swz, int ntc)
{
    __shared__ short As[TM * BKG];
    __shared__ short Bs[TN * BKG];
    int bx = blockIdx.x, by = blockIdx.y;
    if (swz) {
        // XCD-chunked bijective remap (nwg % 8 == 0 for the swizzled call site).
        // Each XCD gets a contiguous bx-chunk, by-fastest, so its B panel
        // plus the whole A matrix (~2 MB) stay L2-resident per XCD.
        const int nx = gridDim.x, ny = gridDim.y;
        const int lin = by * nx + bx;
        const int q = (nx * ny) >> 3;
        const int n = (lin & 7) * q + (lin >> 3);
        bx = n / ny;
        by = n - bx * ny;
    }
    gemm_body(A, lda, B, ldb, K, Cf, Cb, ldc, bias1, bias2, rowbias, bx, by, As, Bs, ntc);
}

// One launch for the three K=2048 init GEMMs (h0, c0, feat-gates). 12 blocks.
__global__ __launch_bounds__(256) void init_gemms(
    const short* __restrict__ featB, const short* __restrict__ iHt,
    const short* __restrict__ iCt, const short* __restrict__ WihB,
    short* __restrict__ h0, float* __restrict__ c0, float* __restrict__ fg,
    const float* __restrict__ initH_b, const float* __restrict__ initC_b,
    const float* __restrict__ b_ih, const float* __restrict__ b_hh)
{
    __shared__ short As[TM * BKG];
    __shared__ short Bs[TN * BKG];
    const int bid = blockIdx.x;
    if (bid < 2)
        gemm_body(featB, F_, iHt, F_, F_, nullptr, h0, H_, initH_b, nullptr, nullptr, bid, 0, As, Bs, 0);
    else if (bid < 4)
        gemm_body(featB, F_, iCt, F_, F_, c0, nullptr, H_, initC_b, nullptr, nullptr, bid - 2, 0, As, Bs, 0);
    else
        gemm_body(featB, F_, WihB + E_, EF, F_, fg, nullptr, G4, b_ih, b_hh, nullptr, bid - 4, 0, As, Bs, 0);
}

// ---------------------------------------------------------------------------
// Batch-partitioned LSTM recurrence — ZERO inter-block communication.
// 32 blocks x 256 threads; block owns batches [4*bx, 4*bx+4).
// W_hh (512 KB bf16) partitioned three ways per step:
//   j =  0..6  : persistent register cache (224 VGPR/lane; total ~420 < 450
//                no-spill threshold [m08/m24] — WG_REG=8 risked spilling)
//   j =  7..10 : persistent LDS cache (128 KB, XOR-swizzled vs bank conflicts)
//   j = 11..15 : streamed from global (L2-hot), 160 KB/block/step; computed
//                LAST so the compiler hoists the loads over the pure-register
//                MFMA groups (~450 cyc of latency cover)
// eg already contains fg + b_ih + b_hh (folded in the eg-GEMM epilogue).
// h lives in LDS (M=16 mfma rows, 4 real); c in registers.
// ---------------------------------------------------------------------------
#define HS 272       // padded h row stride in shorts
#define WG_REG 7     // j-groups cached in registers (j = 0..6)
#define WG_LDS 4     // j-groups cached in LDS (j = 7..10)

__global__ __launch_bounds__(256, 1) void recurrence3(
    const short* __restrict__ Whh,   // (1024 x 256) bf16
    const float* __restrict__ eg,    // (T*B x 1024) fp32: emb gates + fg + biases
    const short* __restrict__ h0,    // (128 x 256) bf16
    const float* __restrict__ c0,    // (128 x 256) fp32
    short* __restrict__ Hall)        // (B*T x 256) bf16, row b*T+t
{
    __shared__ short hs[16 * HS];                    // 8704 B
    __shared__ float Gs[4 * G4];                     // 16384 B
    __shared__ short wlds[WG_LDS * 4 * 16 * 256];    // 131072 B  (total 152.5 KB)
    const int tid  = threadIdx.x;
    const int lane = tid & 63, quad = lane >> 4, l15 = lane & 15, wv = tid >> 6;
    const int b0   = blockIdx.x * 4;
    const int u    = tid;            // pointwise: thread owns unit u, all 4 batches

    // ---- Prologue ----
    // h0 -> LDS (zero the pad rows), c0 -> regs
#pragma unroll
    for (int b = 0; b < 4; b++)
        hs[b * HS + tid] = h0[(size_t)(b0 + b) * H_ + tid];
#pragma unroll
    for (int rr = 4; rr < 16; rr++)
        hs[rr * HS + tid] = 0;
    float c[4];
#pragma unroll
    for (int b = 0; b < 4; b++) c[b] = c0[(size_t)(b0 + b) * H_ + u];

    // LDS W_hh cache fill: 256 rows (4 groups x 4 waves x 16), one row/thread.
    // XOR swizzle (row&7)<<3 shorts on the k-offset, same involution on read.
    {
        const int g = tid >> 6, wv_r = (tid >> 4) & 3, r15 = tid & 15;
        const int grow = wv_r * 256 + (WG_REG + g) * 16 + r15;
        const int swz = (r15 & 7) << 3;
#pragma unroll
        for (int kk = 0; kk < 32; kk++) {
            const bh8 w = *(const bh8*)&Whh[(size_t)grow * H_ + kk * 8];
            *(bh8*)&wlds[tid * 256 + ((kk * 8) ^ swz)] = w;
        }
    }

    // Register W_hh cache: j = 0..6 for this wave's gate cols
    bh8 wcache[WG_REG][8];
#pragma unroll
    for (int j = 0; j < WG_REG; j++) {
        const short* wrow = &Whh[(size_t)(wv * 256 + j * 16 + l15) * H_ + quad * 8];
#pragma unroll
        for (int s = 0; s < 8; s++)
            wcache[j][s] = *(const bh8*)&wrow[s * 32];
    }
    __syncthreads();

    const int swzr = (l15 & 7) << 3;
    const floatx4 zero = {0.f, 0.f, 0.f, 0.f};
    for (int t = 0; t < T_; t++) {
        // Prefetch emb-gate terms early (independent of this step's MFMA)
        float egv[4][4];
#pragma unroll
        for (int b = 0; b < 4; b++)
#pragma unroll
            for (int g = 0; g < 4; g++)
                egv[b][g] = eg[(size_t)(t * B_ + b0 + b) * G4 + g * H_ + u];

        // A-fragments from LDS h (A[m=l15][k=quad*8+j])
        bh8 af[8];
#pragma unroll
        for (int s = 0; s < 8; s++)
            af[s] = *(const bh8*)&hs[l15 * HS + s * 32 + quad * 8];

        // MFMA accumulate. Wave wv covers gate cols [wv*256, wv*256+256).
        floatx4 acc[16];
#pragma unroll
        for (int j = 0; j < 16; j++) acc[j] = zero;
        // j = 0..6 from the register cache (no memory traffic; streamed loads
        // for j=11..15 get hoisted over this window by the scheduler)
#pragma unroll
        for (int j = 0; j < WG_REG; j++)
#pragma unroll
            for (int s = 0; s < 8; s++)
                acc[j] = __builtin_amdgcn_mfma_f32_16x16x32_bf16(
                    af[s], wcache[j][s], acc[j], 0, 0, 0);
        // j = 7..10 from the LDS cache (swizzled)
#pragma unroll
        for (int g = 0; g < WG_LDS; g++) {
            const short* wp = &wlds[((g * 4 + wv) * 16 + l15) * 256];
#pragma unroll
            for (int s = 0; s < 8; s++)
                acc[WG_REG + g] = __builtin_amdgcn_mfma_f32_16x16x32_bf16(
                    af[s], *(const bh8*)&wp[(s * 32 + quad * 8) ^ swzr], acc[WG_REG + g], 0, 0, 0);
        }
        // j = 11..15 streamed from global (L2-hot), last
#pragma unroll
        for (int j = WG_REG + WG_LDS; j < 16; j++) {
            const short* wrow = &Whh[(size_t)(wv * 256 + j * 16 + l15) * H_ + quad * 8];
#pragma unroll
            for (int s = 0; s < 8; s++)
                acc[j] = __builtin_amdgcn_mfma_f32_16x16x32_bf16(
                    af[s], *(const bh8*)&wrow[s * 32], acc[j], 0, 0, 0);
        }

        // Batch rows 0-3 live in quad 0 (row = quad*4 + reg)
        if (quad == 0) {
#pragma unroll
            for (int j = 0; j < 16; j++) {
                const int col = wv * 256 + j * 16 + l15;
#pragma unroll
                for (int r = 0; r < 4; r++)
                    Gs[r * G4 + col] = acc[j][r];
            }
        }
        __syncthreads();

        // LSTM pointwise: unit u, batches 0-3, fp32 state
#pragma unroll
        for (int b = 0; b < 4; b++) {
            const float xi = Gs[b * G4 + u]          + egv[b][0];
            const float xf = Gs[b * G4 + H_ + u]     + egv[b][1];
            const float xg = Gs[b * G4 + 2 * H_ + u] + egv[b][2];
            const float xo = Gs[b * G4 + 3 * H_ + u] + egv[b][3];
            const float ig  = 1.f / (1.f + __expf(-xi));
            const float fgt = 1.f / (1.f + __expf(-xf));
            const float gg  = fast_tanh(xg);
            const float og  = 1.f / (1.f + __expf(-xo));
            c[b] = fgt * c[b] + ig * gg;
            const float h = og * fast_tanh(c[b]);
            const short hb = f2bf(h);
            hs[b * HS + u] = hb;
            Hall[(size_t)((b0 + b) * T_ + t) * H_ + u] = hb;
        }
        __syncthreads();
    }
}

// ---------------------------------------------------------------------------
// Host launcher
// ---------------------------------------------------------------------------
extern "C" void kernel_launch(void* const* d_in, const int* in_sizes, int n_in,
                              void* d_out, int out_size, void* d_ws, size_t ws_size,
                              hipStream_t stream)
{
    (void)in_sizes; (void)n_in; (void)out_size; (void)ws_size;
    const float* features   = (const float*)d_in[0];
    const int*   captions   = (const int*)  d_in[1];
    const float* embeddings = (const float*)d_in[2];
    const float* W_ih       = (const float*)d_in[3];
    const float* b_ih       = (const float*)d_in[4];
    const float* W_hh       = (const float*)d_in[5];
    const float* b_hh       = (const float*)d_in[6];
    const float* fc_W       = (const float*)d_in[7];
    const float* fc_b       = (const float*)d_in[8];
    // d_in[9..14] (Wa/Ua/va): softmax over singleton axis == 1 -> dead.
    const float* initH_W    = (const float*)d_in[15];
    const float* initH_b    = (const float*)d_in[16];
    const float* initC_W    = (const float*)d_in[17];
    const float* initC_b    = (const float*)d_in[18];
    float* out = (float*)d_out;

    char* ws = (char*)d_ws;
    size_t off = 0;
    auto alloc = [&](size_t bytes) -> void* {
        void* p = ws + off; off += (bytes + 255) & ~(size_t)255; return p;
    };
    // X region: eg (fp32, 16.78 MB) during recurrence, then fcWt (bf16, 16.38 MB)
    void*  X      = alloc((size_t)B_ * T_ * G4 * 4);
    float* eg     = (float*)X;
    short* fcWt   = (short*)X;
    short* featB  = (short*)alloc((size_t)B_ * F_ * 2);
    short* WihB   = (short*)alloc((size_t)G4 * EF * 2);
    short* WhhB   = (short*)alloc((size_t)G4 * H_ * 2);
    short* iHt    = (short*)alloc((size_t)H_ * F_ * 2);
    short* iCt    = (short*)alloc((size_t)H_ * F_ * 2);
    short* embB   = (short*)alloc((size_t)B_ * T_ * E_ * 2);
    float* fg     = (float*)alloc((size_t)B_ * G4 * 4);
    short* h0buf  = (short*)alloc((size_t)B_ * H_ * 2);
    float* c0f    = (float*)alloc((size_t)B_ * H_ * 4);
    short* Hall   = (short*)alloc((size_t)B_ * T_ * H_ * 2);
    // total ~28.2 MB

    // Fused prep: all three bf16 converts in one launch, both transposes in one
    cvt3<<<dim3(2688), 256, 0, stream>>>(features, W_ih, W_hh, featB, WihB, WhhB);
    transpose2_f2b<<<dim3(H_ / 64, F_ / 64, 2), 256, 0, stream>>>(initH_W, iHt, initC_W, iCt);
    gather_embed<<<dim3(B_ * T_ / 16), 256, 0, stream>>>(captions, embeddings, embB);

    // h0 / c0 / feat-gates in one 12-block launch
    init_gemms<<<dim3(12), 256, 0, stream>>>(featB, iHt, iCt, WihB,
                                             h0buf, c0f, fg,
                                             initH_b, initC_b, b_ih, b_hh);
    // emb gates for all timesteps: (T*B x 128) @ W_ih[:,:E]^T -> (T*B x 1024),
    // with fg (feat-gates + both biases) folded in per row (rowbias keyed m&127)
    gemm_nt<<<dim3(G4 / TN, B_ * T_ / TM), 256, 0, stream>>>(embB, E_, WihB, EF, E_,
                                                             eg, nullptr, G4, nullptr, nullptr,
                                                             fg, 0, 0);
    // Zero-sync batch-partitioned recurrence (W_hh: 7 j-groups in regs,
    // 4 in LDS, 5 streamed from L2)
    recurrence3<<<dim3(32), 256, 0, stream>>>(WhhB, eg, h0buf, c0f, Hall);

    // eg is dead now; build fc_W^T in the same region, then the big projection
    transpose_f2b<<<dim3(V_ / 64, H_ / 64), 256, 0, stream>>>(fc_W, fcWt, H_, V_);
    // XCD-chunked swizzle (8000 blocks % 8 == 0) + nontemporal fp32 C stores
    gemm_nt<<<dim3(V_ / TN, B_ * T_ / TM), 256, 0, stream>>>(Hall, H_, fcWt, H_, H_,
                                                             out, nullptr, V_, fc_b, nullptr,
                                                             nullptr, 1, 1);
}